// Round 6
// baseline (293.588 us; speedup 1.0000x reference)
//
#include <hip/hip_runtime.h>
#include <hip/hip_bf16.h>

#define DEVI __device__ __forceinline__

typedef __attribute__((ext_vector_type(8))) short bf16x8;
typedef __attribute__((ext_vector_type(4))) float f32x4;

// ---------------------------------------------------------------- helpers
DEVI void load_lds16(const void* g, void* l) {
  // stages 16B per lane: LDS dest = wave-uniform base + lane*16 (linear!)
  __builtin_amdgcn_global_load_lds((const __attribute__((address_space(1))) void*)g,
                                   (__attribute__((address_space(3))) void*)l, 16, 0, 0);
}

DEVI short f32_to_bf16_bits(float f) {
  __hip_bfloat16 b = __float2bfloat16(f);
  return __builtin_bit_cast(short, b);
}

// ---------------------------------------------------------------- prep kernels
__global__ __launch_bounds__(256) void cvt_bf16_kernel(
    const float* __restrict__ in, __hip_bfloat16* __restrict__ out, int n4) {
  int i = blockIdx.x * 256 + threadIdx.x;
  if (i < n4) {
    float4 v = ((const float4*)in)[i];
    ushort4 o;
    o.x = (unsigned short)f32_to_bf16_bits(v.x);
    o.y = (unsigned short)f32_to_bf16_bits(v.y);
    o.z = (unsigned short)f32_to_bf16_bits(v.z);
    o.w = (unsigned short)f32_to_bf16_bits(v.w);
    ((ushort4*)out)[i] = o;
  }
}

// in[K][N] fp32 -> out[N][K] bf16   (block 32x8, grid (N/32, K/32))
__global__ __launch_bounds__(256) void transpose_bf16_kernel(
    const float* __restrict__ in, __hip_bfloat16* __restrict__ out, int K, int N) {
  __shared__ float tile[32][33];
  int tx = threadIdx.x, ty = threadIdx.y;
  int bx = blockIdx.x, by = blockIdx.y;
#pragma unroll
  for (int i = 0; i < 4; ++i) {
    int k = by * 32 + ty + i * 8;
    int n = bx * 32 + tx;
    tile[ty + i * 8][tx] = in[(size_t)k * N + n];
  }
  __syncthreads();
#pragma unroll
  for (int i = 0; i < 4; ++i) {
    int n = bx * 32 + ty + i * 8;
    int k = by * 32 + tx;
    out[(size_t)n * K + k] = __float2bfloat16(tile[tx][ty + i * 8]);
  }
}

// ---------------------------------------------------------------- GEMM
// C[M][N] = A[M][K] * Bt[N][K]^T + bias;  128x128 tile, BK=64, 4 waves.
// LDS XOR-swizzle (16B slots): linear dest + inverse-swizzled source (rule #21).
template <int OUT_BF16>
__global__ __launch_bounds__(256) void gemm_bt_kernel(
    const __hip_bfloat16* __restrict__ A, const __hip_bfloat16* __restrict__ Bt,
    const float* __restrict__ bias, void* __restrict__ Cout, int M, int N, int K) {
  __shared__ short As[128 * 64];
  __shared__ short Bs[128 * 64];
  const int tid = threadIdx.x;
  const int wid = tid >> 6, lane = tid & 63;
  const int bm = blockIdx.y, bn = blockIdx.x;
  const int row0 = bm * 128, col0 = bn * 128;
  const int wr = wid >> 1, wc = wid & 1;  // wave's 64x64 quadrant
  f32x4 acc[4][4] = {};

  for (int kt = 0; kt < K; kt += 64) {
    __syncthreads();
#pragma unroll
    for (int c = 0; c < 4; ++c) {
      int r = wid * 32 + c * 8 + (lane >> 3);      // tile row this lane stages
      int ss = (lane & 7) ^ (r & 7);               // inverse-swizzled source slot
      load_lds16(A + (size_t)(row0 + r) * K + kt + ss * 8, As + (wid * 32 + c * 8) * 64);
      load_lds16(Bt + (size_t)(col0 + r) * K + kt + ss * 8, Bs + (wid * 32 + c * 8) * 64);
    }
    __syncthreads();
#pragma unroll
    for (int ks = 0; ks < 2; ++ks) {
      bf16x8 af[4], bf[4];
#pragma unroll
      for (int mi = 0; mi < 4; ++mi) {
        int r = wr * 64 + mi * 16 + (lane & 15);
        int sl = (ks * 4 + (lane >> 4)) ^ (r & 7);
        af[mi] = *(const bf16x8*)(As + r * 64 + sl * 8);
      }
#pragma unroll
      for (int ni = 0; ni < 4; ++ni) {
        int r = wc * 64 + ni * 16 + (lane & 15);
        int sl = (ks * 4 + (lane >> 4)) ^ (r & 7);
        bf[ni] = *(const bf16x8*)(Bs + r * 64 + sl * 8);
      }
#pragma unroll
      for (int mi = 0; mi < 4; ++mi)
#pragma unroll
        for (int ni = 0; ni < 4; ++ni)
          acc[mi][ni] = __builtin_amdgcn_mfma_f32_16x16x32_bf16(af[mi], bf[ni], acc[mi][ni], 0, 0, 0);
    }
  }
  // epilogue: D col = lane&15, row = (lane>>4)*4 + reg   [m89-verified]
  const int crow0 = row0 + wr * 64, ccol0 = col0 + wc * 64;
#pragma unroll
  for (int ni = 0; ni < 4; ++ni) {
    int cc = ccol0 + ni * 16 + (lane & 15);
    float bv = bias[cc];
#pragma unroll
    for (int mi = 0; mi < 4; ++mi) {
#pragma unroll
      for (int r = 0; r < 4; ++r) {
        int rr = crow0 + mi * 16 + (lane >> 4) * 4 + r;
        float v = acc[mi][ni][r] + bv;
        if (OUT_BF16)
          ((__hip_bfloat16*)Cout)[(size_t)rr * N + cc] = __float2bfloat16(v);
        else
          ((float*)Cout)[(size_t)rr * N + cc] = v;
      }
    }
  }
}

// ---------------------------------------------------------------- flash attention
// qkv: [4096][3072] bf16 (Q|K|V each 1024 cols; head h = cols h*64..h*64+64)
// grid (qb=T/64, b*H+h); 4 waves x 16 q-rows; KV tiles of 64; causal.
__global__ __launch_bounds__(256) void attn_kernel(
    const __hip_bfloat16* __restrict__ qkv, __hip_bfloat16* __restrict__ concat) {
  const int qb = blockIdx.x;
  const int bh = blockIdx.y;
  const int b = bh >> 4, h = bh & 15;
  const int tid = threadIdx.x, wid = tid >> 6, lane = tid & 63;
  const size_t RS = 3072;
  const __hip_bfloat16* Qb = qkv + (size_t)b * 2048 * RS + h * 64;
  const __hip_bfloat16* Kb = Qb + 1024;
  const __hip_bfloat16* Vb = Qb + 2048;

  __shared__ short Ks[64 * 64];      // [key][d], swizzled
  __shared__ short Vt[64 * 64];      // [d][key], swizzled (transposed V)
  __shared__ short Ps[4][16 * 64];   // per-wave P tile [q][key], swizzled

  // Q fragments in registers: A[row=lane&15=q_local][k=d]
  bf16x8 qf[2];
#pragma unroll
  for (int s = 0; s < 2; ++s)
    qf[s] = *(const bf16x8*)(Qb + (size_t)(qb * 64 + wid * 16 + (lane & 15)) * RS + s * 32 + (lane >> 4) * 8);

  f32x4 oacc[4] = {};
  float m_r[4], l_r[4];
#pragma unroll
  for (int r = 0; r < 4; ++r) { m_r[r] = -__builtin_inff(); l_r[r] = 0.f; }

  const float scale = 0.125f;  // 1/sqrt(64)
  for (int kt = 0; kt <= qb; ++kt) {
    __syncthreads();  // previous tile fully consumed
    // --- stage K tile (swizzled global_load_lds, 2 calls/wave)
#pragma unroll
    for (int c = 0; c < 2; ++c) {
      int r = wid * 16 + c * 8 + (lane >> 3);
      int ss = (lane & 7) ^ (r & 7);
      load_lds16(Kb + (size_t)(kt * 64 + r) * RS + ss * 8, Ks + (wid * 16 + c * 8) * 64);
    }
    // --- stage V transposed: thread t -> key = t>>2, d0 = (t&3)*16
    {
      int key = tid >> 2;
      int d0 = (tid & 3) * 16;
      const __hip_bfloat16* vp = Vb + (size_t)(kt * 64 + key) * RS + d0;
      bf16x8 v0 = *(const bf16x8*)(vp);
      bf16x8 v1 = *(const bf16x8*)(vp + 8);
#pragma unroll
      for (int e = 0; e < 8; ++e) {
        int d = d0 + e;
        Vt[d * 64 + (((key >> 3) ^ (d & 7)) * 8) + (key & 7)] = v0[e];
        int d2 = d0 + 8 + e;
        Vt[d2 * 64 + (((key >> 3) ^ (d2 & 7)) * 8) + (key & 7)] = v1[e];
      }
    }
    __syncthreads();  // staging visible (drains vmcnt+lgkm)

    // --- S = Q K^T : acc col = key_local, row = q_local(lane>>4)*4+reg
    f32x4 sacc[4] = {};
#pragma unroll
    for (int s = 0; s < 2; ++s) {
#pragma unroll
      for (int nt = 0; nt < 4; ++nt) {
        int r = nt * 16 + (lane & 15);
        int sl = (s * 4 + (lane >> 4)) ^ (r & 7);
        bf16x8 kf = *(const bf16x8*)(Ks + r * 64 + sl * 8);
        sacc[nt] = __builtin_amdgcn_mfma_f32_16x16x32_bf16(qf[s], kf, sacc[nt], 0, 0, 0);
      }
    }

    // --- scale + causal mask + online softmax (16-lane shuffle reduce)
#pragma unroll
    for (int r = 0; r < 4; ++r) {
      int qg = qb * 64 + wid * 16 + (lane >> 4) * 4 + r;
      float rm = -3.0e38f;
#pragma unroll
      for (int nt = 0; nt < 4; ++nt) {
        float v = sacc[nt][r] * scale;
        int kg = kt * 64 + nt * 16 + (lane & 15);
        v = (kg > qg) ? -1e30f : v;
        sacc[nt][r] = v;
        rm = fmaxf(rm, v);
      }
#pragma unroll
      for (int off = 1; off < 16; off <<= 1) rm = fmaxf(rm, __shfl_xor(rm, off));
      float mn = fmaxf(m_r[r], rm);
      float al = __expf(m_r[r] - mn);
      float rs = 0.f;
#pragma unroll
      for (int nt = 0; nt < 4; ++nt) {
        float p = __expf(sacc[nt][r] - mn);
        sacc[nt][r] = p;
        rs += p;
      }
#pragma unroll
      for (int off = 1; off < 16; off <<= 1) rs += __shfl_xor(rs, off);
      l_r[r] = l_r[r] * al + rs;
      m_r[r] = mn;
#pragma unroll
      for (int dt = 0; dt < 4; ++dt) oacc[dt][r] *= al;
    }

    // --- P -> LDS (bf16, swizzled), then PV MFMA
#pragma unroll
    for (int nt = 0; nt < 4; ++nt)
#pragma unroll
      for (int r = 0; r < 4; ++r) {
        int q = (lane >> 4) * 4 + r;
        int key = nt * 16 + (lane & 15);
        int sl = (key >> 3) ^ (q & 7);
        Ps[wid][q * 64 + sl * 8 + (key & 7)] = f32_to_bf16_bits(sacc[nt][r]);
      }
    __syncthreads();  // P visible (uniform across waves)

#pragma unroll
    for (int s = 0; s < 2; ++s) {
      int q = lane & 15;
      int psl = (s * 4 + (lane >> 4)) ^ (q & 7);
      bf16x8 pf = *(const bf16x8*)(&Ps[wid][q * 64 + psl * 8]);
#pragma unroll
      for (int dt = 0; dt < 4; ++dt) {
        int d = dt * 16 + (lane & 15);
        int vsl = (s * 4 + (lane >> 4)) ^ (d & 7);
        bf16x8 vf = *(const bf16x8*)(&Vt[d * 64 + vsl * 8]);
        oacc[dt] = __builtin_amdgcn_mfma_f32_16x16x32_bf16(pf, vf, oacc[dt], 0, 0, 0);
      }
    }
  }

  // --- normalize + store to concat layout [b*T+t][h*64+d]
  const size_t orow = (size_t)b * 2048;
#pragma unroll
  for (int dt = 0; dt < 4; ++dt)
#pragma unroll
    for (int r = 0; r < 4; ++r) {
      int qg = qb * 64 + wid * 16 + (lane >> 4) * 4 + r;
      float v = oacc[dt][r] / l_r[r];
      concat[(orow + qg) * 1024 + h * 64 + dt * 16 + (lane & 15)] = __float2bfloat16(v);
    }
}

// ---------------------------------------------------------------- launch
extern "C" void kernel_launch(void* const* d_in, const int* in_sizes, int n_in,
                              void* d_out, int out_size, void* d_ws, size_t ws_size,
                              hipStream_t stream) {
  const float* x    = (const float*)d_in[0];
  const float* Wqkv = (const float*)d_in[1];
  const float* bqkv = (const float*)d_in[2];
  const float* Wout = (const float*)d_in[3];
  const float* bout = (const float*)d_in[4];
  float* out = (float*)d_out;

  // Workspace layout (41,943,040 B total). `cat` ALIASES `xb`: xb is dead
  // after the QKV GEMM completes, and attn (which writes cat) is ordered
  // strictly after it on the single stream — zero-risk 8 MB saving.
  char* ws = (char*)d_ws;
  __hip_bfloat16* xb    = (__hip_bfloat16*)(ws);                 //  8,388,608 B  [0, 8M)
  __hip_bfloat16* cat   = (__hip_bfloat16*)(ws);                 //  aliases xb
  __hip_bfloat16* WqkvT = (__hip_bfloat16*)(ws + 8388608);       //  6,291,456 B  [8M, 14M)
  __hip_bfloat16* WoutT = (__hip_bfloat16*)(ws + 14680064);      //  2,097,152 B  [14M, 16M)
  __hip_bfloat16* qkvb  = (__hip_bfloat16*)(ws + 16777216);      // 25,165,824 B  [16M, 40M)

  // x -> bf16
  cvt_bf16_kernel<<<dim3(4096), dim3(256), 0, stream>>>(x, xb, 4194304 / 4);
  // W -> transposed bf16 ([N][K], k-contiguous rows)
  transpose_bf16_kernel<<<dim3(3072 / 32, 1024 / 32), dim3(32, 8), 0, stream>>>(Wqkv, WqkvT, 1024, 3072);
  transpose_bf16_kernel<<<dim3(1024 / 32, 1024 / 32), dim3(32, 8), 0, stream>>>(Wout, WoutT, 1024, 1024);
  // qkv = x @ Wqkv + bqkv   (bf16 out)
  gemm_bt_kernel<1><<<dim3(3072 / 128, 4096 / 128), dim3(256), 0, stream>>>(
      xb, WqkvT, bqkv, (void*)qkvb, 4096, 3072, 1024);
  // causal flash attention -> concat (bf16; overwrites dead xb region)
  attn_kernel<<<dim3(32, 32), dim3(256), 0, stream>>>(qkvb, cat);
  // out = concat @ Wout + bout  (fp32 out)
  gemm_bt_kernel<0><<<dim3(1024 / 128, 4096 / 128), dim3(256), 0, stream>>>(
      cat, WoutT, bout, (void*)out, 4096, 1024, 1024);
}

// Round 9
// 228.159 us; speedup vs baseline: 1.2868x; 1.2868x over previous
//
#include <hip/hip_runtime.h>
#include <hip/hip_bf16.h>

#define DEVI __device__ __forceinline__

typedef __attribute__((ext_vector_type(8))) short bf16x8;
typedef __attribute__((ext_vector_type(4))) float f32x4;

// ---------------------------------------------------------------- helpers
DEVI void load_lds16(const void* g, void* l) {
  // stages 16B per lane: LDS dest = wave-uniform base + lane*16 (linear!)
  __builtin_amdgcn_global_load_lds((const __attribute__((address_space(1))) void*)g,
                                   (__attribute__((address_space(3))) void*)l, 16, 0, 0);
}

DEVI short f32_to_bf16_bits(float f) {
  __hip_bfloat16 b = __float2bfloat16(f);
  return __builtin_bit_cast(short, b);
}

// ---------------------------------------------------------------- prep kernels
__global__ __launch_bounds__(256) void cvt_bf16_kernel(
    const float* __restrict__ in, __hip_bfloat16* __restrict__ out, int n4) {
  int i = blockIdx.x * 256 + threadIdx.x;
  if (i < n4) {
    float4 v = ((const float4*)in)[i];
    ushort4 o;
    o.x = (unsigned short)f32_to_bf16_bits(v.x);
    o.y = (unsigned short)f32_to_bf16_bits(v.y);
    o.z = (unsigned short)f32_to_bf16_bits(v.z);
    o.w = (unsigned short)f32_to_bf16_bits(v.w);
    ((ushort4*)out)[i] = o;
  }
}

// in[K][N] fp32 -> out[N][K] bf16   (block 32x8, grid (N/32, K/32))
__global__ __launch_bounds__(256) void transpose_bf16_kernel(
    const float* __restrict__ in, __hip_bfloat16* __restrict__ out, int K, int N) {
  __shared__ float tile[32][33];
  int tx = threadIdx.x, ty = threadIdx.y;
  int bx = blockIdx.x, by = blockIdx.y;
#pragma unroll
  for (int i = 0; i < 4; ++i) {
    int k = by * 32 + ty + i * 8;
    int n = bx * 32 + tx;
    tile[ty + i * 8][tx] = in[(size_t)k * N + n];
  }
  __syncthreads();
#pragma unroll
  for (int i = 0; i < 4; ++i) {
    int n = bx * 32 + ty + i * 8;
    int k = by * 32 + tx;
    out[(size_t)n * K + k] = __float2bfloat16(tile[tx][ty + i * 8]);
  }
}

// ---------------------------------------------------------------- GEMM
// C = A[M][K] * Bt[N][K]^T + bias;  128x128 tile, BK=64, 4 waves.
// MODE 0: fp32 out, stride N.
// MODE 2: QKV split — cols <2048 -> bf16 qk[token][2048]; cols >=2048 (V) ->
//         transposed vt[bh][d][token] (packed 4-token ushort4 stores).
template <int MODE>
__global__ __launch_bounds__(256) void gemm_bt_kernel(
    const __hip_bfloat16* __restrict__ A, const __hip_bfloat16* __restrict__ Bt,
    const float* __restrict__ bias, void* __restrict__ Cout,
    unsigned short* __restrict__ vt, int M, int N, int K) {
  __shared__ short As[128 * 64];
  __shared__ short Bs[128 * 64];
  const int tid = threadIdx.x;
  const int wid = tid >> 6, lane = tid & 63;
  const int bm = blockIdx.y, bn = blockIdx.x;
  const int row0 = bm * 128, col0 = bn * 128;
  const int wr = wid >> 1, wc = wid & 1;  // wave's 64x64 quadrant
  f32x4 acc[4][4] = {};

  for (int kt = 0; kt < K; kt += 64) {
    __syncthreads();
#pragma unroll
    for (int c = 0; c < 4; ++c) {
      int r = wid * 32 + c * 8 + (lane >> 3);      // tile row this lane stages
      int ss = (lane & 7) ^ (r & 7);               // inverse-swizzled source slot
      load_lds16(A + (size_t)(row0 + r) * K + kt + ss * 8, As + (wid * 32 + c * 8) * 64);
      load_lds16(Bt + (size_t)(col0 + r) * K + kt + ss * 8, Bs + (wid * 32 + c * 8) * 64);
    }
    __syncthreads();
#pragma unroll
    for (int ks = 0; ks < 2; ++ks) {
      bf16x8 af[4], bf[4];
#pragma unroll
      for (int mi = 0; mi < 4; ++mi) {
        int r = wr * 64 + mi * 16 + (lane & 15);
        int sl = (ks * 4 + (lane >> 4)) ^ (r & 7);
        af[mi] = *(const bf16x8*)(As + r * 64 + sl * 8);
      }
#pragma unroll
      for (int ni = 0; ni < 4; ++ni) {
        int r = wc * 64 + ni * 16 + (lane & 15);
        int sl = (ks * 4 + (lane >> 4)) ^ (r & 7);
        bf[ni] = *(const bf16x8*)(Bs + r * 64 + sl * 8);
      }
#pragma unroll
      for (int mi = 0; mi < 4; ++mi)
#pragma unroll
        for (int ni = 0; ni < 4; ++ni)
          acc[mi][ni] = __builtin_amdgcn_mfma_f32_16x16x32_bf16(af[mi], bf[ni], acc[mi][ni], 0, 0, 0);
    }
  }
  // epilogue: D col = lane&15, row = (lane>>4)*4 + reg   [m89-verified]
  const int crow0 = row0 + wr * 64, ccol0 = col0 + wc * 64;
#pragma unroll
  for (int ni = 0; ni < 4; ++ni) {
    int cc = ccol0 + ni * 16 + (lane & 15);
    float bv = bias[cc];
    if (MODE == 2 && cc >= 2048) {
      // V column -> transposed store vt[(b*16+h)*64 + d][token], 4 tokens packed
      int dcol = cc - 2048;
      int hh = dcol >> 6, dl = dcol & 63;
#pragma unroll
      for (int mi = 0; mi < 4; ++mi) {
        int rr0 = crow0 + mi * 16 + (lane >> 4) * 4;   // 4 consecutive tokens
        int bI = rr0 >> 11, t0 = rr0 & 2047;
        ushort4 pk;
        pk.x = (unsigned short)f32_to_bf16_bits(acc[mi][ni][0] + bv);
        pk.y = (unsigned short)f32_to_bf16_bits(acc[mi][ni][1] + bv);
        pk.z = (unsigned short)f32_to_bf16_bits(acc[mi][ni][2] + bv);
        pk.w = (unsigned short)f32_to_bf16_bits(acc[mi][ni][3] + bv);
        *(ushort4*)(vt + ((size_t)(bI * 16 + hh) * 64 + dl) * 2048 + t0) = pk;
      }
    } else {
#pragma unroll
      for (int mi = 0; mi < 4; ++mi) {
#pragma unroll
        for (int r = 0; r < 4; ++r) {
          int rr = crow0 + mi * 16 + (lane >> 4) * 4 + r;
          float v = acc[mi][ni][r] + bv;
          if (MODE == 2)
            ((__hip_bfloat16*)Cout)[(size_t)rr * 2048 + cc] = __float2bfloat16(v);
          else
            ((float*)Cout)[(size_t)rr * N + cc] = v;
        }
      }
    }
  }
}

// ---------------------------------------------------------------- flash attention
// qk: [4096][2048] bf16 (Q|K per token); vt: [32 bh][64 d][2048 t] bf16.
// grid (bh=B*H, qb=T/64)  -- bh fastest so same-head blocks share an XCD L2.
// 4 waves x 16 q-rows; KV tiles of 64, double-buffered; 1 barrier/tile.
__global__ __launch_bounds__(256) void attn_kernel(
    const __hip_bfloat16* __restrict__ qk, const __hip_bfloat16* __restrict__ vt,
    __hip_bfloat16* __restrict__ concat) {
  const int bh = blockIdx.x;
  const int qb = blockIdx.y;
  const int b = bh >> 4, h = bh & 15;
  const int tid = threadIdx.x, wid = tid >> 6, lane = tid & 63;
  const size_t RS = 2048;
  const __hip_bfloat16* Qb = qk + (size_t)b * 2048 * RS + h * 64;
  const __hip_bfloat16* Kb = Qb + 1024;
  const __hip_bfloat16* Vh = vt + (size_t)bh * 64 * 2048;

  __shared__ short Ks[2][64 * 64];   // [key][d], swizzled, double-buffered
  __shared__ short Vs[2][64 * 64];   // [d][key], swizzled, double-buffered
  __shared__ short Ps[4][16 * 64];   // per-wave P tile [q][key], swizzled

  // Q fragments in registers: A[row=lane&15=q_local][k=d]
  bf16x8 qf[2];
#pragma unroll
  for (int s = 0; s < 2; ++s)
    qf[s] = *(const bf16x8*)(Qb + (size_t)(qb * 64 + wid * 16 + (lane & 15)) * RS + s * 32 + (lane >> 4) * 8);

  f32x4 oacc[4] = {};
  float m_r[4], l_r[4];
#pragma unroll
  for (int r = 0; r < 4; ++r) { m_r[r] = -__builtin_inff(); l_r[r] = 0.f; }

  // prologue: stage tile 0 into buffer 0 (K rows + Vt rows, swizzled source)
#pragma unroll
  for (int c = 0; c < 2; ++c) {
    int r = wid * 16 + c * 8 + (lane >> 3);
    int ss = (lane & 7) ^ (r & 7);
    load_lds16(Kb + (size_t)r * RS + ss * 8, &Ks[0][(wid * 16 + c * 8) * 64]);
    load_lds16(Vh + (size_t)r * 2048 + ss * 8, &Vs[0][(wid * 16 + c * 8) * 64]);
  }
  int cur = 0;
  const float cs = 0.18033688f;  // (1/sqrt(64)) * log2(e): softmax in exp2 domain

  for (int kt = 0; kt <= qb; ++kt) {
    __syncthreads();  // drains staging vmcnt -> buf[cur] ready; buf[cur^1] free
    if (kt < qb) {    // prefetch next tile into the other buffer (hidden under compute)
      int kn = kt + 1;
#pragma unroll
      for (int c = 0; c < 2; ++c) {
        int r = wid * 16 + c * 8 + (lane >> 3);
        int ss = (lane & 7) ^ (r & 7);
        load_lds16(Kb + (size_t)(kn * 64 + r) * RS + ss * 8, &Ks[cur ^ 1][(wid * 16 + c * 8) * 64]);
        load_lds16(Vh + (size_t)r * 2048 + kn * 64 + ss * 8, &Vs[cur ^ 1][(wid * 16 + c * 8) * 64]);
      }
    }

    // --- S = Q K^T : acc col = key_local, row = q_local(lane>>4)*4+reg
    f32x4 sacc[4] = {};
#pragma unroll
    for (int s = 0; s < 2; ++s) {
#pragma unroll
      for (int nt = 0; nt < 4; ++nt) {
        int r = nt * 16 + (lane & 15);
        int sl = (s * 4 + (lane >> 4)) ^ (r & 7);
        bf16x8 kf = *(const bf16x8*)(&Ks[cur][r * 64 + sl * 8]);
        sacc[nt] = __builtin_amdgcn_mfma_f32_16x16x32_bf16(qf[s], kf, sacc[nt], 0, 0, 0);
      }
    }

    // --- online softmax (exp2 domain); mask only the diagonal tile
    const bool diag = (kt == qb);
#pragma unroll
    for (int r = 0; r < 4; ++r) {
      int qg = wid * 16 + (lane >> 4) * 4 + r;  // local q row (0..63)
      float rm = -3.0e38f;
#pragma unroll
      for (int nt = 0; nt < 4; ++nt) {
        float v = sacc[nt][r] * cs;
        if (diag) {
          int kg = nt * 16 + (lane & 15);
          v = (kg > qg) ? -1e30f : v;
        }
        sacc[nt][r] = v;
        rm = fmaxf(rm, v);
      }
#pragma unroll
      for (int off = 1; off < 16; off <<= 1) rm = fmaxf(rm, __shfl_xor(rm, off));
      float mn = fmaxf(m_r[r], rm);
      float al = exp2f(m_r[r] - mn);
      float rs = 0.f;
#pragma unroll
      for (int nt = 0; nt < 4; ++nt) {
        float p = exp2f(sacc[nt][r] - mn);
        sacc[nt][r] = p;
        rs += p;
      }
#pragma unroll
      for (int off = 1; off < 16; off <<= 1) rs += __shfl_xor(rs, off);
      l_r[r] = l_r[r] * al + rs;
      m_r[r] = mn;
#pragma unroll
      for (int dt = 0; dt < 4; ++dt) oacc[dt][r] *= al;
    }

    // --- P -> LDS (per-wave region; same-wave ds ordering, no barrier needed)
#pragma unroll
    for (int nt = 0; nt < 4; ++nt)
#pragma unroll
      for (int r = 0; r < 4; ++r) {
        int q = (lane >> 4) * 4 + r;
        int key = nt * 16 + (lane & 15);
        int sl = (key >> 3) ^ (q & 7);
        Ps[wid][q * 64 + sl * 8 + (key & 7)] = f32_to_bf16_bits(sacc[nt][r]);
      }

    // --- PV MFMA
#pragma unroll
    for (int s = 0; s < 2; ++s) {
      int q = lane & 15;
      int psl = (s * 4 + (lane >> 4)) ^ (q & 7);
      bf16x8 pf = *(const bf16x8*)(&Ps[wid][q * 64 + psl * 8]);
#pragma unroll
      for (int dt = 0; dt < 4; ++dt) {
        int d = dt * 16 + (lane & 15);
        int vsl = (s * 4 + (lane >> 4)) ^ (d & 7);
        bf16x8 vf = *(const bf16x8*)(&Vs[cur][d * 64 + vsl * 8]);
        oacc[dt] = __builtin_amdgcn_mfma_f32_16x16x32_bf16(pf, vf, oacc[dt], 0, 0, 0);
      }
    }
    cur ^= 1;
  }

  // --- normalize + store to concat layout [b*T+t][h*64+d]
  const size_t orow = (size_t)b * 2048;
#pragma unroll
  for (int dt = 0; dt < 4; ++dt)
#pragma unroll
    for (int r = 0; r < 4; ++r) {
      int qg = qb * 64 + wid * 16 + (lane >> 4) * 4 + r;
      float v = oacc[dt][r] / l_r[r];
      concat[(orow + qg) * 1024 + h * 64 + dt * 16 + (lane & 15)] = __float2bfloat16(v);
    }
}

// ---------------------------------------------------------------- launch
extern "C" void kernel_launch(void* const* d_in, const int* in_sizes, int n_in,
                              void* d_out, int out_size, void* d_ws, size_t ws_size,
                              hipStream_t stream) {
  const float* x    = (const float*)d_in[0];
  const float* Wqkv = (const float*)d_in[1];
  const float* bqkv = (const float*)d_in[2];
  const float* Wout = (const float*)d_in[3];
  const float* bout = (const float*)d_in[4];
  float* out = (float*)d_out;

  // Workspace layout, 40 MB total (proven budget 41.94 MB):
  //  [0,8M):    xb (bf16 x) -> dead after QKV GEMM -> cat (attn output), aliased
  //  [8M,14M):  WqkvT
  //  [14M,16M): WoutT
  //  [16M,32M): qkvqk [4096][2048] bf16 (Q|K)
  //  [32M,40M): vt    [32][64][2048] bf16 (V transposed per head)
  char* ws = (char*)d_ws;
  __hip_bfloat16* xb    = (__hip_bfloat16*)(ws);
  __hip_bfloat16* cat   = (__hip_bfloat16*)(ws);            // aliases xb (sequential)
  __hip_bfloat16* WqkvT = (__hip_bfloat16*)(ws + 8388608);
  __hip_bfloat16* WoutT = (__hip_bfloat16*)(ws + 14680064);
  __hip_bfloat16* qkvqk = (__hip_bfloat16*)(ws + 16777216);
  __hip_bfloat16* vtb   = (__hip_bfloat16*)(ws + 33554432);

  // x -> bf16
  cvt_bf16_kernel<<<dim3(4096), dim3(256), 0, stream>>>(x, xb, 4194304 / 4);
  // W -> transposed bf16 ([N][K], k-contiguous rows)
  transpose_bf16_kernel<<<dim3(3072 / 32, 1024 / 32), dim3(32, 8), 0, stream>>>(Wqkv, WqkvT, 1024, 3072);
  transpose_bf16_kernel<<<dim3(1024 / 32, 1024 / 32), dim3(32, 8), 0, stream>>>(Wout, WoutT, 1024, 1024);
  // qkv = x @ Wqkv + bqkv;  Q|K -> qkvqk, V -> vt (transposed per head)
  gemm_bt_kernel<2><<<dim3(3072 / 128, 4096 / 128), dim3(256), 0, stream>>>(
      xb, WqkvT, bqkv, (void*)qkvqk, (unsigned short*)vtb, 4096, 3072, 1024);
  // causal flash attention -> concat (bf16; overwrites dead xb region)
  attn_kernel<<<dim3(32, 32), dim3(256), 0, stream>>>(qkvqk, vtb, cat);
  // out = concat @ Wout + bout  (fp32 out)
  gemm_bt_kernel<0><<<dim3(1024 / 128, 4096 / 128), dim3(256), 0, stream>>>(
      cat, WoutT, bout, (void*)out, nullptr, 4096, 1024, 1024);
}

// Round 12
// 207.784 us; speedup vs baseline: 1.4129x; 1.0981x over previous
//
#include <hip/hip_runtime.h>
#include <hip/hip_bf16.h>

#define DEVI __device__ __forceinline__

typedef __attribute__((ext_vector_type(8))) short bf16x8;
typedef __attribute__((ext_vector_type(4))) float f32x4;
typedef __attribute__((ext_vector_type(16))) float f32x16;

// ---------------------------------------------------------------- helpers
DEVI void load_lds16(const void* g, void* l) {
  // stages 16B per lane: LDS dest = wave-uniform base + lane*16 (linear!)
  __builtin_amdgcn_global_load_lds((const __attribute__((address_space(1))) void*)g,
                                   (__attribute__((address_space(3))) void*)l, 16, 0, 0);
}

DEVI short f32_to_bf16_bits(float f) {
  __hip_bfloat16 b = __float2bfloat16(f);
  return __builtin_bit_cast(short, b);
}

DEVI unsigned pk_bf16(float lo, float hi) {  // {hi:bf16(hi), lo:bf16(lo)}
  unsigned r;
  asm("v_cvt_pk_bf16_f32 %0, %1, %2" : "=v"(r) : "v"(lo), "v"(hi));
  return r;
}

// ---------------------------------------------------------------- prep kernels
__global__ __launch_bounds__(256) void cvt_bf16_kernel(
    const float* __restrict__ in, __hip_bfloat16* __restrict__ out, int n4) {
  int i = blockIdx.x * 256 + threadIdx.x;
  if (i < n4) {
    float4 v = ((const float4*)in)[i];
    ushort4 o;
    o.x = (unsigned short)f32_to_bf16_bits(v.x);
    o.y = (unsigned short)f32_to_bf16_bits(v.y);
    o.z = (unsigned short)f32_to_bf16_bits(v.z);
    o.w = (unsigned short)f32_to_bf16_bits(v.w);
    ((ushort4*)out)[i] = o;
  }
}

// in[K][N] fp32 -> out[N][K] bf16   (block 32x8, grid (N/32, K/32))
__global__ __launch_bounds__(256) void transpose_bf16_kernel(
    const float* __restrict__ in, __hip_bfloat16* __restrict__ out, int K, int N) {
  __shared__ float tile[32][33];
  int tx = threadIdx.x, ty = threadIdx.y;
  int bx = blockIdx.x, by = blockIdx.y;
#pragma unroll
  for (int i = 0; i < 4; ++i) {
    int k = by * 32 + ty + i * 8;
    int n = bx * 32 + tx;
    tile[ty + i * 8][tx] = in[(size_t)k * N + n];
  }
  __syncthreads();
#pragma unroll
  for (int i = 0; i < 4; ++i) {
    int n = bx * 32 + ty + i * 8;
    int k = by * 32 + tx;
    out[(size_t)n * K + k] = __float2bfloat16(tile[tx][ty + i * 8]);
  }
}

// ---------------------------------------------------------------- GEMM
// C = A[M][K] * Bt[N][K]^T + bias;  128x128 tile, BK=64, 4 waves.
// MODE 0: fp32 out, stride N.
// MODE 2: QKV split — cols <2048 -> bf16 qk[token][2048]; cols >=2048 (V) ->
//         transposed vt[bh][d][token] (packed 4-token ushort4 stores).
template <int MODE>
__global__ __launch_bounds__(256) void gemm_bt_kernel(
    const __hip_bfloat16* __restrict__ A, const __hip_bfloat16* __restrict__ Bt,
    const float* __restrict__ bias, void* __restrict__ Cout,
    unsigned short* __restrict__ vt, int M, int N, int K) {
  __shared__ short As[128 * 64];
  __shared__ short Bs[128 * 64];
  const int tid = threadIdx.x;
  const int wid = tid >> 6, lane = tid & 63;
  const int bm = blockIdx.y, bn = blockIdx.x;
  const int row0 = bm * 128, col0 = bn * 128;
  const int wr = wid >> 1, wc = wid & 1;  // wave's 64x64 quadrant
  f32x4 acc[4][4] = {};

  for (int kt = 0; kt < K; kt += 64) {
    __syncthreads();
#pragma unroll
    for (int c = 0; c < 4; ++c) {
      int r = wid * 32 + c * 8 + (lane >> 3);      // tile row this lane stages
      int ss = (lane & 7) ^ (r & 7);               // inverse-swizzled source slot
      load_lds16(A + (size_t)(row0 + r) * K + kt + ss * 8, As + (wid * 32 + c * 8) * 64);
      load_lds16(Bt + (size_t)(col0 + r) * K + kt + ss * 8, Bs + (wid * 32 + c * 8) * 64);
    }
    __syncthreads();
#pragma unroll
    for (int ks = 0; ks < 2; ++ks) {
      bf16x8 af[4], bf[4];
#pragma unroll
      for (int mi = 0; mi < 4; ++mi) {
        int r = wr * 64 + mi * 16 + (lane & 15);
        int sl = (ks * 4 + (lane >> 4)) ^ (r & 7);
        af[mi] = *(const bf16x8*)(As + r * 64 + sl * 8);
      }
#pragma unroll
      for (int ni = 0; ni < 4; ++ni) {
        int r = wc * 64 + ni * 16 + (lane & 15);
        int sl = (ks * 4 + (lane >> 4)) ^ (r & 7);
        bf[ni] = *(const bf16x8*)(Bs + r * 64 + sl * 8);
      }
#pragma unroll
      for (int mi = 0; mi < 4; ++mi)
#pragma unroll
        for (int ni = 0; ni < 4; ++ni)
          acc[mi][ni] = __builtin_amdgcn_mfma_f32_16x16x32_bf16(af[mi], bf[ni], acc[mi][ni], 0, 0, 0);
    }
  }
  // epilogue: D col = lane&15, row = (lane>>4)*4 + reg   [m89-verified]
  const int crow0 = row0 + wr * 64, ccol0 = col0 + wc * 64;
#pragma unroll
  for (int ni = 0; ni < 4; ++ni) {
    int cc = ccol0 + ni * 16 + (lane & 15);
    float bv = bias[cc];
    if (MODE == 2 && cc >= 2048) {
      // V column -> transposed store vt[(b*16+h)*64 + d][token], 4 tokens packed
      int dcol = cc - 2048;
      int hh = dcol >> 6, dl = dcol & 63;
#pragma unroll
      for (int mi = 0; mi < 4; ++mi) {
        int rr0 = crow0 + mi * 16 + (lane >> 4) * 4;   // 4 consecutive tokens
        int bI = rr0 >> 11, t0 = rr0 & 2047;
        ushort4 pk;
        pk.x = (unsigned short)f32_to_bf16_bits(acc[mi][ni][0] + bv);
        pk.y = (unsigned short)f32_to_bf16_bits(acc[mi][ni][1] + bv);
        pk.z = (unsigned short)f32_to_bf16_bits(acc[mi][ni][2] + bv);
        pk.w = (unsigned short)f32_to_bf16_bits(acc[mi][ni][3] + bv);
        *(ushort4*)(vt + ((size_t)(bI * 16 + hh) * 64 + dl) * 2048 + t0) = pk;
      }
    } else {
#pragma unroll
      for (int mi = 0; mi < 4; ++mi) {
#pragma unroll
        for (int r = 0; r < 4; ++r) {
          int rr = crow0 + mi * 16 + (lane >> 4) * 4 + r;
          float v = acc[mi][ni][r] + bv;
          if (MODE == 2)
            ((__hip_bfloat16*)Cout)[(size_t)rr * 2048 + cc] = __float2bfloat16(v);
          else
            ((float*)Cout)[(size_t)rr * N + cc] = v;
        }
      }
    }
  }
}

// ---------------------------------------------------------------- flash attention
// qk: [4096][2048] bf16 (Q|K); vt: [32 bh][64 d][2048 t] bf16.
// 32x32x16 MFMA, swapped QK^T (S^T: q=lane&31, key=reg) -> in-register softmax
// (31 in-lane ops + 1 shfl_xor(32)); P stays in regs: cvt_pk pairs + lane+-32
// exchange build the PV B-frag. 4 waves x 32 q = 128 q/block; KVBLK=64, dbuf.
// grid (bh=32, qblk=16), long blocks (high qblk) launched first.
__global__ __launch_bounds__(256) void attn_kernel(
    const __hip_bfloat16* __restrict__ qk, const __hip_bfloat16* __restrict__ vt,
    __hip_bfloat16* __restrict__ concat) {
  const int bh = blockIdx.x;
  const int jr = 15 - (int)blockIdx.y;     // reversed: longest blocks first
  const int qb0 = jr * 128;
  const int NT = 2 * jr + 2;               // kv tiles this block needs
  const int b = bh >> 4, h = bh & 15;
  const int tid = threadIdx.x, wid = tid >> 6, lane = tid & 63;
  const int ql = lane & 31, hl = lane >> 5;
  const size_t RS = 2048;
  const __hip_bfloat16* Qb = qk + (size_t)b * 2048 * RS + h * 64;
  const __hip_bfloat16* Kb = Qb + 1024;
  const __hip_bfloat16* Vh = vt + (size_t)bh * 64 * 2048;

  __shared__ short Ks[2][64 * 64];   // [key][d], swizzled, double-buffered
  __shared__ short Vs[2][64 * 64];   // [d][key], swizzled, double-buffered

  // Q as B-frag (col=q=lane&31, k=d=(lane>>5)*8+e per 16-k step): identical
  // per-lane data to an A-frag load at 32-row granularity.
  const int qrow = qb0 + wid * 32 + ql;    // this lane's q token
  bf16x8 qf[4];
#pragma unroll
  for (int s = 0; s < 4; ++s)
    qf[s] = *(const bf16x8*)(Qb + (size_t)qrow * RS + s * 16 + hl * 8);

  f32x16 oacc[2] = {};                     // O^T: col=q, row=d (per 32-d block)
  float m = -__builtin_inff(), l = 0.f;
  const float cs = 0.18033688f;            // (1/sqrt(64)) * log2(e)

  // prologue: stage tile 0 into buffer 0
#pragma unroll
  for (int c = 0; c < 2; ++c) {
    int r = wid * 16 + c * 8 + (lane >> 3);
    int ss = (lane & 7) ^ (r & 7);
    load_lds16(Kb + (size_t)r * RS + ss * 8, &Ks[0][(wid * 16 + c * 8) * 64]);
    load_lds16(Vh + (size_t)r * 2048 + ss * 8, &Vs[0][(wid * 16 + c * 8) * 64]);
  }
  int cur = 0;
  const int ktmax = (qb0 + 32 * wid + 31) >> 6;  // wave's last active tile

  for (int kt = 0; kt < NT; ++kt) {
    __syncthreads();  // buf[cur] staged; buf[cur^1] free
    if (kt + 1 < NT) {
      int kn = kt + 1;
#pragma unroll
      for (int c = 0; c < 2; ++c) {
        int r = wid * 16 + c * 8 + (lane >> 3);
        int ss = (lane & 7) ^ (r & 7);
        load_lds16(Kb + (size_t)(kn * 64 + r) * RS + ss * 8, &Ks[cur ^ 1][(wid * 16 + c * 8) * 64]);
        load_lds16(Vh + (size_t)r * 2048 + kn * 64 + ss * 8, &Vs[cur ^ 1][(wid * 16 + c * 8) * 64]);
      }
    }
    if (kt <= ktmax) {  // wave-uniform: skip fully-masked tiles
      // --- S^T = K Q^T : col=q=lane&31, key=kb*32+(r&3)+8*(r>>2)+4*hl
      f32x16 sacc[2] = {};
#pragma unroll
      for (int s = 0; s < 4; ++s)
#pragma unroll
        for (int kb = 0; kb < 2; ++kb) {
          int row = kb * 32 + ql;
          int slot = (2 * s + hl) ^ (ql & 7);
          bf16x8 kf = *(const bf16x8*)(&Ks[cur][row * 64 + slot * 8]);
          sacc[kb] = __builtin_amdgcn_mfma_f32_32x32x16_bf16(kf, qf[s], sacc[kb], 0, 0, 0);
        }
      // --- causal mask (diag tiles only; raw-S domain)
      if (kt * 64 + 63 > qb0 + 32 * wid) {
#pragma unroll
        for (int kb = 0; kb < 2; ++kb)
#pragma unroll
          for (int r = 0; r < 16; ++r) {
            int kg = kt * 64 + kb * 32 + (r & 3) + 8 * (r >> 2) + 4 * hl;
            if (kg > qrow) sacc[kb][r] = -1e30f;
          }
      }
      // --- in-register online softmax (per-lane q; 1 cross-lane hop)
      float rm = -3.0e38f;
#pragma unroll
      for (int kb = 0; kb < 2; ++kb)
#pragma unroll
        for (int r = 0; r < 16; ++r) rm = fmaxf(rm, sacc[kb][r]);
      rm = fmaxf(rm, __shfl_xor(rm, 32));
      float mn = fmaxf(m, rm);
      float al = exp2f((m - mn) * cs);
      float mcs = mn * cs;
      float rs = 0.f;
#pragma unroll
      for (int kb = 0; kb < 2; ++kb)
#pragma unroll
        for (int r = 0; r < 16; ++r) {
          float p = exp2f(fmaf(sacc[kb][r], cs, -mcs));
          sacc[kb][r] = p;
          rs += p;
        }
      rs += __shfl_xor(rs, 32);
      l = l * al + rs;
      m = mn;
#pragma unroll
      for (int db = 0; db < 2; ++db)
#pragma unroll
        for (int r = 0; r < 16; ++r) oacc[db][r] *= al;

      // --- P -> bf16 B-frags in registers (cvt_pk + lane+-32 exchange), PV
#pragma unroll
      for (int kk = 0; kk < 4; ++kk) {
        int kb = kk >> 1;
        int be = 8 * (kk & 1);
        unsigned x0 = pk_bf16(sacc[kb][be + 0], sacc[kb][be + 1]);
        unsigned x1 = pk_bf16(sacc[kb][be + 2], sacc[kb][be + 3]);
        unsigned y0 = pk_bf16(sacc[kb][be + 4], sacc[kb][be + 5]);
        unsigned y1 = pk_bf16(sacc[kb][be + 6], sacc[kb][be + 7]);
        unsigned x0p = __shfl_xor(x0, 32), x1p = __shfl_xor(x1, 32);
        unsigned y0p = __shfl_xor(y0, 32), y1p = __shfl_xor(y1, 32);
        union { unsigned u[4]; bf16x8 v; } pb;
        pb.u[0] = hl ? y0p : x0;    // keys kk*16+8*hl+{0,1}
        pb.u[1] = hl ? y1p : x1;    // +{2,3}
        pb.u[2] = hl ? y0 : x0p;    // +{4,5}
        pb.u[3] = hl ? y1 : x1p;    // +{6,7}
#pragma unroll
        for (int db = 0; db < 2; ++db) {
          int row = db * 32 + ql;
          int slot = (2 * kk + hl) ^ (ql & 7);
          bf16x8 vf = *(const bf16x8*)(&Vs[cur][row * 64 + slot * 8]);
          oacc[db] = __builtin_amdgcn_mfma_f32_32x32x16_bf16(vf, pb.v, oacc[db], 0, 0, 0);
        }
      }
    }
    cur ^= 1;
  }

  // --- normalize + store (O^T: per lane 1 q, d = db*32+8*rr+4*hl+{0..3})
  float rl = 1.0f / l;
  const size_t orow = (size_t)b * 2048 + qrow;
#pragma unroll
  for (int db = 0; db < 2; ++db)
#pragma unroll
    for (int rr = 0; rr < 4; ++rr) {
      int d0 = db * 32 + 8 * rr + 4 * hl;
      ushort4 pkv;
      pkv.x = (unsigned short)f32_to_bf16_bits(oacc[db][4 * rr + 0] * rl);
      pkv.y = (unsigned short)f32_to_bf16_bits(oacc[db][4 * rr + 1] * rl);
      pkv.z = (unsigned short)f32_to_bf16_bits(oacc[db][4 * rr + 2] * rl);
      pkv.w = (unsigned short)f32_to_bf16_bits(oacc[db][4 * rr + 3] * rl);
      *(ushort4*)(concat + orow * 1024 + h * 64 + d0) = pkv;
    }
}

// ---------------------------------------------------------------- launch
extern "C" void kernel_launch(void* const* d_in, const int* in_sizes, int n_in,
                              void* d_out, int out_size, void* d_ws, size_t ws_size,
                              hipStream_t stream) {
  const float* x    = (const float*)d_in[0];
  const float* Wqkv = (const float*)d_in[1];
  const float* bqkv = (const float*)d_in[2];
  const float* Wout = (const float*)d_in[3];
  const float* bout = (const float*)d_in[4];
  float* out = (float*)d_out;

  // Workspace layout, 40 MB total (proven budget 41.94 MB):
  //  [0,8M):    xb (bf16 x) -> dead after QKV GEMM -> cat (attn output), aliased
  //  [8M,14M):  WqkvT
  //  [14M,16M): WoutT
  //  [16M,32M): qkvqk [4096][2048] bf16 (Q|K)
  //  [32M,40M): vt    [32][64][2048] bf16 (V transposed per head)
  char* ws = (char*)d_ws;
  __hip_bfloat16* xb    = (__hip_bfloat16*)(ws);
  __hip_bfloat16* cat   = (__hip_bfloat16*)(ws);            // aliases xb (sequential)
  __hip_bfloat16* WqkvT = (__hip_bfloat16*)(ws + 8388608);
  __hip_bfloat16* WoutT = (__hip_bfloat16*)(ws + 14680064);
  __hip_bfloat16* qkvqk = (__hip_bfloat16*)(ws + 16777216);
  __hip_bfloat16* vtb   = (__hip_bfloat16*)(ws + 33554432);

  // x -> bf16
  cvt_bf16_kernel<<<dim3(4096), dim3(256), 0, stream>>>(x, xb, 4194304 / 4);
  // W -> transposed bf16 ([N][K], k-contiguous rows)
  transpose_bf16_kernel<<<dim3(3072 / 32, 1024 / 32), dim3(32, 8), 0, stream>>>(Wqkv, WqkvT, 1024, 3072);
  transpose_bf16_kernel<<<dim3(1024 / 32, 1024 / 32), dim3(32, 8), 0, stream>>>(Wout, WoutT, 1024, 1024);
  // qkv = x @ Wqkv + bqkv;  Q|K -> qkvqk, V -> vt (transposed per head)
  gemm_bt_kernel<2><<<dim3(3072 / 128, 4096 / 128), dim3(256), 0, stream>>>(
      xb, WqkvT, bqkv, (void*)qkvqk, (unsigned short*)vtb, 4096, 3072, 1024);
  // causal flash attention -> concat (bf16; overwrites dead xb region)
  attn_kernel<<<dim3(32, 16), dim3(256), 0, stream>>>(qkvqk, vtb, cat);
  // out = concat @ Wout + bout  (fp32 out)
  gemm_bt_kernel<0><<<dim3(1024 / 128, 4096 / 128), dim3(256), 0, stream>>>(
      cat, WoutT, bout, (void*)out, nullptr, 4096, 1024, 1024);
}